// Round 10
// baseline (17.935 us; speedup 1.0000x reference)
//
#include <hip/hip_runtime.h>
#include <cmath>

typedef float v2f __attribute__((ext_vector_type(2)));

#define B_    4
#define CIN   8
#define COUT  16
#define H_    192
#define W_    192
#define T_    16                 // 16x16 output tile
#define SXc   20                 // slab row: 16 + 4 halo
#define SYc   20
#define SLAB  (SYc * SXc)        // 400 floats
#define NF2   (SLAB / 2)         // 200 float2
#define NT    128
#define CHAN_F2 (H_ * W_ / 2)    // 18432

__global__ __launch_bounds__(NT, 4)
void semiconv_kernel(const float* __restrict__ x,
                     const float* __restrict__ scales,
                     float* __restrict__ out) {
    __shared__ __align__(16) float tile[CIN * SLAB];   // 12800 B
    __shared__ __align__(16) float wtab[CIN][COUT];    // 512 B  [ci][co]

    int blk = blockIdx.x;
    const int tile_x = blk % 12; blk /= 12;
    const int tile_y = blk % 12; blk /= 12;
    const int b      = blk;

    const int tid = threadIdx.x;
    const int py  = tid >> 3;          // 0..15 output row
    const int q   = tid & 7;           // col-pair; output cols 2q, 2q+1

    // weight table: exactly one divide per thread (128 = CIN*COUT)
    {
        const int ci = tid >> 4, co = tid & 15;
        wtab[ci][co] = 0.25f / scales[co * CIN + ci];
    }

    // ---- staging coords (float2): elements tid, tid+128 of 200 ----
    const int gy0  = tile_y * T_ - 2;
    const int gxp0 = tile_x * (T_ / 2) - 1;
    int gidx[2]; bool okk[2];
    #pragma unroll
    for (int k = 0; k < 2; ++k) {
        const int e  = tid + k * NT;
        const int ey = e / 10, ex = e - ey * 10;
        const int gy = gy0 + ey, gxp = gxp0 + ex;
        okk[k]  = (gy >= 0) && (gy < H_) && (gxp >= 0) && (gxp < W_ / 2);
        gidx[k] = gy * (W_ / 2) + gxp;
    }
    const bool tail = tid < (NF2 - NT);   // 72 threads

    // ---- load all 8 slabs to regs (all loads in flight), write LDS ----
    const float2* xb = (const float2*)(x + (size_t)b * CIN * H_ * W_);
    const float2 NEG2 = make_float2(-INFINITY, -INFINITY);
    float2 pf[CIN][2];
    #pragma unroll
    for (int ci = 0; ci < CIN; ++ci) {
        const float2* xp = xb + ci * CHAN_F2;
        pf[ci][0] = okk[0] ? xp[gidx[0]] : NEG2;
        pf[ci][1] = (tail && okk[1]) ? xp[gidx[1]] : NEG2;
    }
    float2* lp = (float2*)tile;
    #pragma unroll
    for (int ci = 0; ci < CIN; ++ci) {
        lp[ci * NF2 + tid] = pf[ci][0];
        if (tail) lp[ci * NF2 + tid + NT] = pf[ci][1];
    }

    __syncthreads();   // the only barrier

    v2f acc[COUT];
    #pragma unroll
    for (int co = 0; co < COUT; ++co) acc[co] = (v2f){0.f, 0.f};

    const float* tb = tile + py * SXc + 2 * q;

    #pragma unroll
    for (int ci = 0; ci < CIN; ++ci) {
        const float* tp = tb + ci * SLAB;

        // 5 rows x 6 cols window via 3x b64 per row (8B-aligned, uniform banks)
        float X[5][6];
        #pragma unroll
        for (int r = 0; r < 5; ++r) {
            v2f xa = *(const v2f*)(tp + r * SXc);
            v2f xm = *(const v2f*)(tp + r * SXc + 2);
            v2f xc = *(const v2f*)(tp + r * SXc + 4);
            X[r][0] = xa.x; X[r][1] = xa.y;
            X[r][2] = xm.x; X[r][3] = xm.y;
            X[r][4] = xc.x; X[r][5] = xc.y;
        }

        // vertical class partials (co-independent)
        float V0[6], V1[6], V4[6];
        #pragma unroll
        for (int c = 0; c < 6; ++c) {
            V0[c] = X[2][c];
            V1[c] = fmaxf(X[1][c], X[3][c]);
            V4[c] = fmaxf(X[0][c], X[4][c]);
        }

        // horizontal class maxes for the pixel pair (halo centers c=2,3)
        v2f M0 = (v2f){V0[2], V0[3]};
        v2f M1 = (v2f){fmaxf(fmaxf(V0[1], V0[3]), V1[2]),
                       fmaxf(fmaxf(V0[2], V0[4]), V1[3])};
        v2f M2 = (v2f){fmaxf(V1[1], V1[3]),
                       fmaxf(V1[2], V1[4])};
        v2f M4 = (v2f){fmaxf(fmaxf(V0[0], V0[4]), V4[2]),
                       fmaxf(fmaxf(V0[1], V0[5]), V4[3])};
        v2f M5 = (v2f){fmaxf(fmaxf(V1[0], V1[4]), fmaxf(V4[1], V4[3])),
                       fmaxf(fmaxf(V1[1], V1[5]), fmaxf(V4[2], V4[4]))};
        v2f M8 = (v2f){fmaxf(V4[0], V4[4]),
                       fmaxf(V4[1], V4[5])};

        // per-block-uniform weights: 4x b128 broadcast reads
        const float4* wr = (const float4*)&wtab[ci][0];
        const float4 w0 = wr[0], w1 = wr[1], w2 = wr[2], w3 = wr[3];

        #pragma unroll
        for (int co = 0; co < COUT; ++co) {
            const float4 wv = (co < 4) ? w0 : (co < 8) ? w1 : (co < 12) ? w2 : w3;
            const float a  = (&wv.x)[co & 3];
            const v2f aa = (v2f){a, a};
            v2f s1 = M1 - aa;
            v2f s2 = M2 - 2.f * aa;      // v_pk_fma_f32
            v2f s4 = M4 - 4.f * aa;
            v2f s5 = M5 - 5.f * aa;
            v2f s8 = M8 - 8.f * aa;
            v2f vm;
            vm.x = fmaxf(fmaxf(fmaxf(s1.x, s2.x), M0.x),
                         fmaxf(fmaxf(s4.x, s5.x), s8.x));
            vm.y = fmaxf(fmaxf(fmaxf(s1.y, s2.y), M0.y),
                         fmaxf(fmaxf(s4.y, s5.y), s8.y));
            acc[co] += vm;
        }
    }

    const int gy = tile_y * T_ + py;
    const int gx = tile_x * T_ + 2 * q;
    #pragma unroll
    for (int co = 0; co < COUT; ++co) {
        float* op = out + ((size_t)((b * COUT + co) * H_) + gy) * W_ + gx;
        *(v2f*)op = acc[co];
    }
}

extern "C" void kernel_launch(void* const* d_in, const int* in_sizes, int n_in,
                              void* d_out, int out_size, void* d_ws, size_t ws_size,
                              hipStream_t stream) {
    const float* x      = (const float*)d_in[0];
    const float* scales = (const float*)d_in[1];
    float* out          = (float*)d_out;

    const int n_blocks = B_ * (H_ / T_) * (W_ / T_);  // 4*12*12 = 576
    semiconv_kernel<<<n_blocks, NT, 0, stream>>>(x, scales, out);
}

// Round 11
// 16.649 us; speedup vs baseline: 1.0772x; 1.0772x over previous
//
#include <hip/hip_runtime.h>
#include <cmath>

typedef float v2f __attribute__((ext_vector_type(2)));

#define B_    4
#define CIN   8
#define COUT  16
#define H_    192
#define W_    192
#define T_    16                 // 16x16 output tile
#define SXc   20                 // 16 + 4 halo
#define SLAB  400                // 20*20 floats per ci slab
#define NF2   200                // float2 per slab
#define NT    512
#define CHAN_F2 (H_ * W_ / 2)    // 18432

__global__ __launch_bounds__(NT, 4)
void semiconv_kernel(const float* __restrict__ x,
                     const float* __restrict__ scales,
                     float* __restrict__ out) {
    __shared__ __align__(16) float tile[CIN * SLAB];        // 12800 B
    __shared__ __align__(16) float wtab[CIN][COUT];         // 512 B [ci][co]
    __shared__ __align__(16) float cbuf[3][COUT][128][2];   // 49152 B

    int blk = blockIdx.x;
    const int tile_x = blk % 12; blk /= 12;
    const int tile_y = blk % 12; blk /= 12;
    const int b      = blk;

    const int tid = threadIdx.x;
    const int grp = tid >> 7;          // 0..3: handles ci = 2*grp, 2*grp+1
    const int lt  = tid & 127;
    const int py  = lt >> 3;           // 0..15 output row
    const int q   = lt & 7;            // px-pair: cols 2q, 2q+1

    // weight table: one divide per (ci,co), 128 threads
    if (tid < CIN * COUT) {
        const int ci = tid >> 4, co = tid & 15;
        wtab[ci][co] = 0.25f / scales[co * CIN + ci];
    }

    // ---- staging: threads 0..399, each stages f2-elem of 4 slabs ----
    if (tid < 2 * NF2) {
        const int sg   = (tid >= NF2) ? 1 : 0;
        const int elem = tid - sg * NF2;
        const int ey   = elem / 10, ex = elem - ey * 10;
        const int gy   = tile_y * T_ - 2 + ey;
        const int gxp  = tile_x * (T_ / 2) - 1 + ex;
        const bool ok  = (gy >= 0) && (gy < H_) && (gxp >= 0) && (gxp < W_ / 2);
        const int gofs = gy * (W_ / 2) + gxp;
        const float2* xb = (const float2*)(x + (size_t)b * CIN * H_ * W_)
                           + (size_t)sg * 4 * CHAN_F2;
        const float2 NEG2 = make_float2(-INFINITY, -INFINITY);
        float2 v[4];
        #pragma unroll
        for (int k = 0; k < 4; ++k)
            v[k] = ok ? xb[k * CHAN_F2 + gofs] : NEG2;
        float2* lp = (float2*)tile + sg * 4 * NF2;
        #pragma unroll
        for (int k = 0; k < 4; ++k)
            lp[k * NF2 + elem] = v[k];
    }

    __syncthreads();

    v2f acc[COUT];
    #pragma unroll
    for (int co = 0; co < COUT; ++co) acc[co] = (v2f){0.f, 0.f};

    const float* tb = tile + py * SXc + 2 * q;

    #pragma unroll
    for (int k = 0; k < 2; ++k) {
        const int ci = 2 * grp + k;
        const float* tp = tb + ci * SLAB;

        // 5 rows x 6 cols window via 3x b64 per row
        float X[5][6];
        #pragma unroll
        for (int r = 0; r < 5; ++r) {
            v2f xa = *(const v2f*)(tp + r * SXc);
            v2f xm = *(const v2f*)(tp + r * SXc + 2);
            v2f xc = *(const v2f*)(tp + r * SXc + 4);
            X[r][0] = xa.x; X[r][1] = xa.y;
            X[r][2] = xm.x; X[r][3] = xm.y;
            X[r][4] = xc.x; X[r][5] = xc.y;
        }

        // vertical class partials (co-independent)
        float V0[6], V1[6], V4[6];
        #pragma unroll
        for (int c = 0; c < 6; ++c) {
            V0[c] = X[2][c];
            V1[c] = fmaxf(X[1][c], X[3][c]);
            V4[c] = fmaxf(X[0][c], X[4][c]);
        }

        // horizontal class maxes for the px pair (centers c=2,3)
        v2f M0 = (v2f){V0[2], V0[3]};
        v2f M1 = (v2f){fmaxf(fmaxf(V0[1], V0[3]), V1[2]),
                       fmaxf(fmaxf(V0[2], V0[4]), V1[3])};
        v2f M2 = (v2f){fmaxf(V1[1], V1[3]),
                       fmaxf(V1[2], V1[4])};
        v2f M4 = (v2f){fmaxf(fmaxf(V0[0], V0[4]), V4[2]),
                       fmaxf(fmaxf(V0[1], V0[5]), V4[3])};
        v2f M5 = (v2f){fmaxf(fmaxf(V1[0], V1[4]), fmaxf(V4[1], V4[3])),
                       fmaxf(fmaxf(V1[1], V1[5]), fmaxf(V4[2], V4[4]))};
        v2f M8 = (v2f){fmaxf(V4[0], V4[4]),
                       fmaxf(V4[1], V4[5])};

        const float4* wr = (const float4*)&wtab[ci][0];
        const float4 w0 = wr[0], w1 = wr[1], w2 = wr[2], w3 = wr[3];

        #pragma unroll
        for (int co = 0; co < COUT; ++co) {
            const float4 wv = (co < 4) ? w0 : (co < 8) ? w1 : (co < 12) ? w2 : w3;
            const float a  = (&wv.x)[co & 3];
            const v2f aa = (v2f){a, a};
            v2f s1 = M1 - aa;
            v2f s2 = M2 - 2.f * aa;      // v_pk_fma_f32
            v2f s4 = M4 - 4.f * aa;
            v2f s5 = M5 - 5.f * aa;
            v2f s8 = M8 - 8.f * aa;
            v2f vm;
            vm.x = fmaxf(fmaxf(fmaxf(s1.x, s2.x), M0.x),
                         fmaxf(fmaxf(s4.x, s5.x), s8.x));
            vm.y = fmaxf(fmaxf(fmaxf(s1.y, s2.y), M0.y),
                         fmaxf(fmaxf(s4.y, s5.y), s8.y));
            acc[co] += vm;
        }
    }

    // ---- combine 4 ci-partials ----
    if (grp != 0) {
        #pragma unroll
        for (int co = 0; co < COUT; ++co)
            *(v2f*)&cbuf[grp - 1][co][lt][0] = acc[co];
    }
    __syncthreads();
    if (grp == 0) {
        const int gy = tile_y * T_ + py;
        const int gx = tile_x * T_ + 2 * q;
        #pragma unroll
        for (int co = 0; co < COUT; ++co) {
            v2f s = acc[co];
            #pragma unroll
            for (int g = 0; g < 3; ++g)
                s += *(const v2f*)&cbuf[g][co][lt][0];
            float* op = out + ((size_t)((b * COUT + co) * H_) + gy) * W_ + gx;
            *(v2f*)op = s;
        }
    }
}

extern "C" void kernel_launch(void* const* d_in, const int* in_sizes, int n_in,
                              void* d_out, int out_size, void* d_ws, size_t ws_size,
                              hipStream_t stream) {
    const float* x      = (const float*)d_in[0];
    const float* scales = (const float*)d_in[1];
    float* out          = (float*)d_out;

    const int n_blocks = B_ * (H_ / T_) * (W_ / T_);  // 4*12*12 = 576
    semiconv_kernel<<<n_blocks, NT, 0, stream>>>(x, scales, out);
}

// Round 12
// 16.086 us; speedup vs baseline: 1.1149x; 1.0350x over previous
//
#include <hip/hip_runtime.h>
#include <cmath>

typedef float v2f __attribute__((ext_vector_type(2)));

#define B_    4
#define CIN   8
#define COUT  16
#define H_    192
#define W_    192
#define TW    32
#define TH    16
#define SX    36
#define SY    20
#define SLAB  (SY * SX)          // 720 floats per ci slab
#define NF2   (SLAB / 2)         // 360
#define NCO   8
#define NT    512
#define CHAN_F2 (H_ * W_ / 2)    // 18432

__global__ __launch_bounds__(NT, 4)
void semiconv_kernel(const float* __restrict__ x,
                     const float* __restrict__ scales,
                     float* __restrict__ out) {
    __shared__ __align__(16) float tile[CIN * SLAB];          // 23040 B
    __shared__ __align__(16) float wtab[CIN][NCO];            // 256 B [ci][co]
    __shared__ __align__(16) float cbuf[3 * NCO * 128 * 4];   // 49152 B

    int blk = blockIdx.x;
    const int tile_x = blk % 6;  blk /= 6;
    const int tile_y = blk % 12; blk /= 12;
    const int cg     = blk & 1;  blk >>= 1;
    const int b      = blk;

    const int tid = threadIdx.x;
    const int lt  = tid & 127;
    const int grp = tid >> 7;          // 0..3; handles ci = 2*grp, 2*grp+1
    const int py  = lt >> 3;           // 0..15 output row
    const int p0  = (lt & 7) * 4;      // output col group

    if (tid < CIN * NCO) {             // wtab[ci][co] = 0.25/s
        int ci = tid >> 3, co = tid & 7;
        wtab[ci][co] = 0.25f / scales[(cg * NCO + co) * CIN + ci];
    }

    // ---- staging: threads 0..359 stage float2-elem `tid` of ALL 8 slabs ----
    if (tid < NF2) {
        const int ey  = tid / 18, ex = tid - (tid / 18) * 18;
        const int gy  = tile_y * TH - 2 + ey;
        const int gxp = tile_x * (TW / 2) - 1 + ex;
        const bool ok = (gy >= 0) && (gy < H_) && (gxp >= 0) && (gxp < W_ / 2);
        const int gofs = gy * (W_ / 2) + gxp;
        const float2* xb = (const float2*)(x + (size_t)b * CIN * H_ * W_);
        const float2 NEG2 = make_float2(-INFINITY, -INFINITY);
        float2 v[CIN];
        #pragma unroll
        for (int ci = 0; ci < CIN; ++ci)
            v[ci] = ok ? xb[ci * CHAN_F2 + gofs] : NEG2;
        float2* lp = (float2*)tile;
        #pragma unroll
        for (int ci = 0; ci < CIN; ++ci)
            lp[ci * NF2 + tid] = v[ci];
    }

    __syncthreads();

    v2f acc[NCO][2];
    #pragma unroll
    for (int co = 0; co < NCO; ++co) {
        acc[co][0] = (v2f){0.f, 0.f};
        acc[co][1] = (v2f){0.f, 0.f};
    }

    const float* tbg = tile + grp * 2 * SLAB + py * SX + p0;

    #pragma unroll
    for (int k = 0; k < 2; ++k) {
        const float* tp = tbg + k * SLAB;

        float X[5][8];
        #pragma unroll
        for (int r = 0; r < 5; ++r) {
            float4 lo = *(const float4*)(tp + r * SX);
            float4 hi = *(const float4*)(tp + r * SX + 4);
            X[r][0] = lo.x; X[r][1] = lo.y; X[r][2] = lo.z; X[r][3] = lo.w;
            X[r][4] = hi.x; X[r][5] = hi.y; X[r][6] = hi.z; X[r][7] = hi.w;
        }

        // vertical class partials (co-independent)
        float V0[8], V1[8], V4[8];
        #pragma unroll
        for (int c = 0; c < 8; ++c) {
            V0[c] = X[2][c];
            V1[c] = fmaxf(X[1][c], X[3][c]);
            V4[c] = fmaxf(X[0][c], X[4][c]);
        }

        // horizontal class maxes, packed per px-pair (pr0: c=2,3; pr1: c=4,5)
        v2f M0[2], M1[2], M2[2], M4[2], M5[2], M8[2];
        #pragma unroll
        for (int pr = 0; pr < 2; ++pr) {
            const int c0 = 2 + 2 * pr;
            M0[pr] = (v2f){V0[c0], V0[c0 + 1]};
            M1[pr] = (v2f){fmaxf(fmaxf(V0[c0 - 1], V0[c0 + 1]), V1[c0]),
                           fmaxf(fmaxf(V0[c0],     V0[c0 + 2]), V1[c0 + 1])};
            M2[pr] = (v2f){fmaxf(V1[c0 - 1], V1[c0 + 1]),
                           fmaxf(V1[c0],     V1[c0 + 2])};
            M4[pr] = (v2f){fmaxf(fmaxf(V0[c0 - 2], V0[c0 + 2]), V4[c0]),
                           fmaxf(fmaxf(V0[c0 - 1], V0[c0 + 3]), V4[c0 + 1])};
            M5[pr] = (v2f){fmaxf(fmaxf(fmaxf(V1[c0 - 2], V1[c0 + 2]), V4[c0 - 1]), V4[c0 + 1]),
                           fmaxf(fmaxf(fmaxf(V1[c0 - 1], V1[c0 + 3]), V4[c0]),     V4[c0 + 2])};
            M8[pr] = (v2f){fmaxf(V4[c0 - 2], V4[c0 + 2]),
                           fmaxf(V4[c0 - 1], V4[c0 + 3])};
        }

        const float* wrow = &wtab[grp * 2 + k][0];
        float4 wv0 = *(const float4*)(wrow);
        float4 wv1 = *(const float4*)(wrow + 4);

        #pragma unroll
        for (int co = 0; co < NCO; ++co) {
            const float a = (co < 4) ? (&wv0.x)[co] : (&wv1.x)[co - 4];
            const v2f aa = (v2f){a, a};
            #pragma unroll
            for (int pr = 0; pr < 2; ++pr) {
                v2f s1 = M1[pr] - aa;              // pk_add(neg)
                v2f s2 = M2[pr] - 2.f * aa;        // pk_fma
                v2f s4 = M4[pr] - 4.f * aa;        // pk_fma
                v2f s5 = M5[pr] - 5.f * aa;        // pk_fma
                v2f s8 = M8[pr] - 8.f * aa;        // pk_fma
                float lox = fmaxf(fmaxf(s1.x, s2.x), M0[pr].x);   // max3
                float hix = fmaxf(fmaxf(s4.x, s5.x), s8.x);       // max3
                float loy = fmaxf(fmaxf(s1.y, s2.y), M0[pr].y);
                float hiy = fmaxf(fmaxf(s4.y, s5.y), s8.y);
                v2f vm;
                vm.x = fmaxf(lox, hix);
                vm.y = fmaxf(loy, hiy);
                acc[co][pr] += vm;                 // pk_add
            }
        }
    }

    // ---- combine the 4 ci-partials ----
    if (grp != 0) {
        float* cb = cbuf + (((grp - 1) * NCO) * 128 + lt) * 4;
        #pragma unroll
        for (int co = 0; co < NCO; ++co) {
            float* p = cb + co * 128 * 4;
            *(v2f*)p       = acc[co][0];
            *(v2f*)(p + 2) = acc[co][1];
        }
    }
    __syncthreads();
    if (grp == 0) {
        const int gy = tile_y * TH + py;
        const int gx = tile_x * TW + p0;
        #pragma unroll
        for (int co = 0; co < NCO; ++co) {
            #pragma unroll
            for (int g = 1; g < 4; ++g) {
                float4 t = *(const float4*)(cbuf + (((g - 1) * NCO + co) * 128 + lt) * 4);
                acc[co][0] += (v2f){t.x, t.y};
                acc[co][1] += (v2f){t.z, t.w};
            }
            float4 o;
            o.x = acc[co][0].x; o.y = acc[co][0].y;
            o.z = acc[co][1].x; o.w = acc[co][1].y;
            float* op = out + ((size_t)((b * COUT + cg * NCO + co) * H_) + gy) * W_ + gx;
            *(float4*)op = o;
        }
    }
}

extern "C" void kernel_launch(void* const* d_in, const int* in_sizes, int n_in,
                              void* d_out, int out_size, void* d_ws, size_t ws_size,
                              hipStream_t stream) {
    const float* x      = (const float*)d_in[0];
    const float* scales = (const float*)d_in[1];
    float* out          = (float*)d_out;

    const int n_blocks = B_ * 2 * (H_ / TH) * (W_ / TW);  // 4*2*12*6 = 576
    semiconv_kernel<<<n_blocks, NT, 0, stream>>>(x, scales, out);
}